// Round 1
// baseline (718.439 us; speedup 1.0000x reference)
//
#include <hip/hip_runtime.h>
#include <math.h>

#define K 8192
#define BROWS 4096
#define ALPHA 0.5f

__device__ __forceinline__ void argmax_combine(float& v, int& i, float v2, int i2){
  if (v2 > v || (v2 == v && i2 < i)) { v = v2; i = i2; }
}

// One block (256 threads, 4 waves) per row. Row of outputs (8192 fp32 = 32/thread)
// is held in registers across all passes so outputs is read from HBM exactly once.
__global__ __launch_bounds__(256) void row_stats_kernel(
    const float* __restrict__ outputs,
    const float* __restrict__ targets,
    const float* __restrict__ S,
    float* __restrict__ rowloss,
    int*   __restrict__ rowtl,
    int*   __restrict__ rowcorrect,
    float* __restrict__ rowm,
    float* __restrict__ rowinvZ)
{
  const int b = blockIdx.x;
  const int t = threadIdx.x;
  const int lane = t & 63;
  const int wid  = t >> 6;

  const float4* orow = (const float4*)(outputs + (size_t)b * K);
  float x[32];
#pragma unroll
  for (int i = 0; i < 8; ++i){
    float4 v = orow[i*256 + t];
    x[4*i+0]=v.x; x[4*i+1]=v.y; x[4*i+2]=v.z; x[4*i+3]=v.w;
  }

  // local argmax over outputs (first-occurrence tie-break via index compare)
  float mv = -INFINITY; int mi = 0x7fffffff;
#pragma unroll
  for (int i = 0; i < 8; ++i){
#pragma unroll
    for (int c = 0; c < 4; ++c){
      int idx = i*1024 + t*4 + c;
      argmax_combine(mv, mi, x[4*i+c], idx);
    }
  }

  // targets pass: argmax(targets) -> tl, plus generic hard-CE partial dots
  const float4* trow = (const float4*)(targets + (size_t)b * K);
  float tv = -INFINITY; int ti = 0x7fffffff;
  float d_hard = 0.f, s_hard = 0.f;
#pragma unroll
  for (int i = 0; i < 8; ++i){
    float4 v = trow[i*256 + t];
    float tc[4] = {v.x, v.y, v.z, v.w};
#pragma unroll
    for (int c = 0; c < 4; ++c){
      int idx = i*1024 + t*4 + c;
      d_hard += x[4*i+c] * tc[c];
      s_hard += tc[c];
      argmax_combine(tv, ti, tc[c], idx);
    }
  }

  // wave-level argmax reductions (both pairs together)
#pragma unroll
  for (int off = 32; off; off >>= 1){
    float v2 = __shfl_down(mv, off, 64); int i2 = __shfl_down(mi, off, 64);
    argmax_combine(mv, mi, v2, i2);
    v2 = __shfl_down(tv, off, 64); i2 = __shfl_down(ti, off, 64);
    argmax_combine(tv, ti, v2, i2);
  }

  __shared__ float s_v[2][4]; __shared__ int s_i[2][4];
  __shared__ float s_m; __shared__ int s_pred; __shared__ int s_tl;
  if (lane == 0){ s_v[0][wid]=mv; s_i[0][wid]=mi; s_v[1][wid]=tv; s_i[1][wid]=ti; }
  __syncthreads();
  if (t == 0){
    float av=s_v[0][0]; int ai=s_i[0][0];
    float bv=s_v[1][0]; int bi=s_i[1][0];
#pragma unroll
    for (int w=1; w<4; ++w){
      argmax_combine(av, ai, s_v[0][w], s_i[0][w]);
      argmax_combine(bv, bi, s_v[1][w], s_i[1][w]);
    }
    s_m = av; s_pred = ai; s_tl = bi;
  }
  __syncthreads();
  const float m  = s_m;
  const int   tl = s_tl;

  // sum exp(x - m) from registers
  float se = 0.f;
#pragma unroll
  for (int i = 0; i < 32; ++i) se += expf(x[i] - m);

  // soft-CE dot against S[tl] row
  const float4* srow = (const float4*)(S + (size_t)tl * K);
  float d_soft = 0.f, s_soft = 0.f;
#pragma unroll
  for (int i = 0; i < 8; ++i){
    float4 v = srow[i*256 + t];
    d_soft += x[4*i+0]*v.x + x[4*i+1]*v.y + x[4*i+2]*v.z + x[4*i+3]*v.w;
    s_soft += v.x + v.y + v.z + v.w;
  }

  // block-reduce the 5 sums
  float sums[5] = {d_hard, s_hard, se, d_soft, s_soft};
#pragma unroll
  for (int off = 32; off; off >>= 1){
#pragma unroll
    for (int j = 0; j < 5; ++j) sums[j] += __shfl_down(sums[j], off, 64);
  }
  __shared__ float s_sums[4][5];
  if (lane == 0){
#pragma unroll
    for (int j = 0; j < 5; ++j) s_sums[wid][j] = sums[j];
  }
  __syncthreads();
  if (t == 0){
    float tot[5];
#pragma unroll
    for (int j=0;j<5;++j) tot[j] = s_sums[0][j]+s_sums[1][j]+s_sums[2][j]+s_sums[3][j];
    float Z = tot[2];
    float logZ = logf(Z);
    // sum(ls * w) = d - (m + logZ) * s   where ls = x - m - logZ
    float ceh = -(tot[0] - (m + logZ) * tot[1]);
    float ces = -(tot[3] - (m + logZ) * tot[4]);
    rowloss[b]    = (ALPHA * ceh + (1.0f - ALPHA) * ces) * (1.0f / (float)BROWS);
    rowtl[b]      = tl;
    rowcorrect[b] = (s_pred == tl) ? 1 : 0;
    rowm[b]       = m;
    rowinvZ[b]    = 1.0f / Z;
  }
}

// S_t (256 MB) -> out_St copy. dst = d_out+1 is only 4B-aligned, so scalar dword
// copy (fully coalesced per instruction). Grid 8192 x 256 x 32 elems = 64M exact.
__global__ __launch_bounds__(256) void copy_st_kernel(const float* __restrict__ src,
                                                      float* __restrict__ dst){
  size_t base = (size_t)blockIdx.x * 8192 + threadIdx.x;
#pragma unroll
  for (int j = 0; j < 32; ++j)
    dst[base + (size_t)j*256] = src[base + (size_t)j*256];
}

// Deterministic loss reduction + count copy (single block).
__global__ __launch_bounds__(256) void loss_count_kernel(const float* __restrict__ rowloss,
                                                         const float* __restrict__ count,
                                                         float* __restrict__ out_loss,
                                                         float* __restrict__ out_count){
  int t = threadIdx.x;
  float s = 0.f;
  for (int i = t; i < BROWS; i += 256) s += rowloss[i];
#pragma unroll
  for (int off = 32; off; off >>= 1) s += __shfl_down(s, off, 64);
  __shared__ float sh[4];
  if ((t & 63) == 0) sh[t >> 6] = s;
  __syncthreads();
  if (t == 0) out_loss[0] = sh[0] + sh[1] + sh[2] + sh[3];
  for (int i = t; i < K; i += 256) out_count[i] = count[i];
}

// Scatter probs for correct rows (expected ~0-2 rows of 4096; early exit otherwise).
// atomicAdd handles multiple correct rows sharing a label.
__global__ __launch_bounds__(256) void scatter_kernel(const float* __restrict__ outputs,
    const int* __restrict__ rowtl, const int* __restrict__ rowcorrect,
    const float* __restrict__ rowm, const float* __restrict__ rowinvZ,
    float* __restrict__ out_St, float* __restrict__ out_count){
  int b = blockIdx.x;
  if (!rowcorrect[b]) return;
  int tl = rowtl[b];
  float m = rowm[b], invZ = rowinvZ[b];
  const float* orow = outputs + (size_t)b * K;
  float* drow = out_St + (size_t)tl * K;
  for (int k = threadIdx.x; k < K; k += 256)
    atomicAdd(&drow[k], expf(orow[k] - m) * invZ);
  if (threadIdx.x == 0) atomicAdd(&out_count[tl], 1.0f);
}

extern "C" void kernel_launch(void* const* d_in, const int* in_sizes, int n_in,
                              void* d_out, int out_size, void* d_ws, size_t ws_size,
                              hipStream_t stream) {
  const float* outputs = (const float*)d_in[0];
  const float* targets = (const float*)d_in[1];
  const float* S       = (const float*)d_in[2];
  const float* S_t     = (const float*)d_in[3];
  const float* count   = (const float*)d_in[4];

  float* out       = (float*)d_out;
  float* out_loss  = out;
  float* out_St    = out + 1;
  float* out_count = out + 1 + (size_t)K * K;

  float* rowloss    = (float*)d_ws;            // B floats
  float* rowm       = rowloss + BROWS;         // B floats
  float* rowinvZ    = rowm + BROWS;            // B floats
  int*   rowtl      = (int*)(rowinvZ + BROWS); // B ints
  int*   rowcorrect = rowtl + BROWS;           // B ints

  hipLaunchKernelGGL(row_stats_kernel, dim3(BROWS), dim3(256), 0, stream,
                     outputs, targets, S, rowloss, rowtl, rowcorrect, rowm, rowinvZ);
  hipLaunchKernelGGL(copy_st_kernel, dim3(8192), dim3(256), 0, stream, S_t, out_St);
  hipLaunchKernelGGL(loss_count_kernel, dim3(1), dim3(256), 0, stream,
                     rowloss, count, out_loss, out_count);
  hipLaunchKernelGGL(scatter_kernel, dim3(BROWS), dim3(256), 0, stream,
                     outputs, rowtl, rowcorrect, rowm, rowinvZ, out_St, out_count);
}